// Round 1
// baseline (694.119 us; speedup 1.0000x reference)
//
#include <hip/hip_runtime.h>
#include <hip/hip_fp8.h>

typedef __bf16 bf16_t;
typedef __bf16 bf16x8 __attribute__((ext_vector_type(8)));
typedef float floatx16 __attribute__((ext_vector_type(16)));
typedef int intx8 __attribute__((ext_vector_type(8)));
typedef unsigned long long u64;

#define B_ 16
#define N_ 4096
#define K_ 32

// ws layout (bytes):
//   idx   u16 [16][4096][32]         @ 0        (4194304)
//   g_enc u32 [16][1024]             @ 4194304  (65536)
//   w3f8  fp8 frag-major [131072]    @ 4259840  (131072)   (= w3 * 16)
//   w2sw  bf16 frag-major [8192]     @ 4390912  (16384)
//   tmat  f32 [16][9]                @ 4407296  (576)

__device__ __forceinline__ unsigned enc_f(float f) {
    unsigned u = __float_as_uint(f);
    return (u & 0x80000000u) ? ~u : (u | 0x80000000u);
}
__device__ __forceinline__ float dec_f(unsigned e) {
    return __uint_as_float((e & 0x80000000u) ? (e & 0x7fffffffu) : ~e);
}

// ---------------------------------------------------------------------------
// K1: kNN top-32 (r13 core, unchanged).  16 threads/query x 256 candidates,
// register top-8, unconditional med3-chain insert, two-level 4-way merges.
// grid 2048 x 512.  Side jobs: zero g_enc, build w3f8 + w2sw.
// ---------------------------------------------------------------------------
__global__ __launch_bounds__(512, 4) void knn_kernel(
    const float* __restrict__ x, const float* __restrict__ w3,
    const float* __restrict__ w2, unsigned short* __restrict__ idxb,
    unsigned* __restrict__ g_enc, unsigned char* __restrict__ w3f8,
    bf16_t* __restrict__ w2sw)
{
    __shared__ __align__(16) float4 cand[16 * 257];   // 65792 B
    unsigned* lists = (unsigned*)cand;                // reused after scan
    unsigned* m1 = ((unsigned*)cand) + 8192;          // merge scratch @ 32 KB
    const int tid = threadIdx.x;
    const int bid = blockIdx.x;  // 2048 blocks

    {
        const int g = bid * 512 + tid;
        if (g < 131072) {
            const int q = g & 15, lI = (g >> 4) & 63, mt2 = (g >> 10) & 3, cb = g >> 12;
            const int lmI = lI & 31, hiI = lI >> 5;
            const int ch = mt2 * 32 + (q & 3) + 8 * (q >> 2) + 4 * hiI;
            __hip_fp8_e4m3 t(16.0f * w3[(cb * 32 + lmI) * 128 + ch]);
            w3f8[g] = t.__x;
        } else if (g < 139264) {
            const int o = g - 131072;
            const int f = o >> 9, r = o & 511, lI = r >> 3, jj = r & 7;
            const int ks = f & 3, nb = f >> 2, lmI = lI & 31, hiI = lI >> 5;
            w2sw[o] = (bf16_t)w2[(nb * 32 + lmI) * 64 + ks * 16 + hiI * 8 + jj];
        } else if (g < 155648) {
            g_enc[g - 139264] = 0u;
        }
    }

    const int b  = bid >> 7;                    // 128 blocks per batch
    const int q  = tid >> 4;                    // local query 0..31
    const int n  = (bid & 127) * 32 + q;        // global query index
    const int t  = tid & 15;                    // candidate chunk
    const float* xb = x + b * 3 * N_;

    for (int j = tid; j < N_; j += 512) {
        float cx = xb[j], cy = xb[N_ + j], cz = xb[2 * N_ + j];
        cand[j + (j >> 8)] = make_float4(-2.f * cx, -2.f * cy, -2.f * cz,
                                         fmaf(cx, cx, fmaf(cy, cy, cz * cz)));
    }
    __syncthreads();

    const float xi0 = xb[n], xi1 = xb[N_ + n], xi2 = xb[2 * N_ + n];
    const float xisq1 = fmaf(xi0, xi0, fmaf(xi1, xi1, xi2 * xi2)) + 1.0f;

    unsigned r[8];
    #pragma unroll
    for (int s = 0; s < 8; s++) r[s] = 0x7F7FFFFFu;   // FLT_MAX sentinel

    const int j0 = t * 256;
    const int pb = t * 257;
    #pragma unroll 8
    for (int jj = 0; jj < 256; jj++) {
        const float4 c = cand[pb + jj];
        const float d = fmaf(c.z, xi2, fmaf(c.y, xi1, fmaf(c.x, xi0, c.w)));
        const unsigned key =
            (__float_as_uint(d + xisq1) & 0xFFFFF000u) | (unsigned)(j0 + jj);
        #pragma unroll
        for (int s = 7; s >= 1; s--) {
            const unsigned hv = r[s - 1] > key ? r[s - 1] : key;
            r[s] = r[s] < hv ? r[s] : hv;           // med3
        }
        r[0] = r[0] < key ? r[0] : key;
    }
    __syncthreads();

    #pragma unroll
    for (int k = 0; k < 8; k++) lists[tid * 9 + k] = r[k];
    __syncthreads();

    if (tid < 128) {
        const int q1 = tid >> 2, gi = tid & 3;
        const int base = (q1 * 16 + gi * 4) * 9;
        unsigned h0 = lists[base], h1 = lists[base + 9];
        unsigned h2 = lists[base + 18], h3 = lists[base + 27];
        int p0 = 0, p1 = 0, p2 = 0, p3 = 0;
        unsigned* outp = m1 + (q1 * 4 + gi) * 32;
        #pragma unroll 1
        for (int k = 0; k < 32; k++) {
            const unsigned m01 = h0 < h1 ? h0 : h1;
            const unsigned m23 = h2 < h3 ? h2 : h3;
            const unsigned v = m01 < m23 ? m01 : m23;
            outp[k] = v;
            if (m01 < m23) {
                if (h1 < h0) { p1++; h1 = p1 < 8 ? lists[base + 9 + p1] : 0xFFFFFFFFu; }
                else         { p0++; h0 = p0 < 8 ? lists[base + p0]     : 0xFFFFFFFFu; }
            } else {
                if (h3 < h2) { p3++; h3 = p3 < 8 ? lists[base + 27 + p3] : 0xFFFFFFFFu; }
                else         { p2++; h2 = p2 < 8 ? lists[base + 18 + p2] : 0xFFFFFFFFu; }
            }
        }
    }
    __syncthreads();

    if (tid < 32) {
        const unsigned* g0 = m1 + tid * 128;
        unsigned h0 = g0[0], h1 = g0[32], h2 = g0[64], h3 = g0[96];
        int p0 = 0, p1 = 0, p2 = 0, p3 = 0;
        const int nq = (bid & 127) * 32 + tid;
        unsigned short* op = idxb + ((size_t)(b * N_ + nq)) * K_;
        #pragma unroll 1
        for (int k = 0; k < K_; k++) {
            const unsigned m01 = h0 < h1 ? h0 : h1;
            const unsigned m23 = h2 < h3 ? h2 : h3;
            const unsigned v = m01 < m23 ? m01 : m23;
            op[k] = (unsigned short)(v & 0xFFFu);
            if (m01 < m23) {
                if (h1 < h0) { p1++; h1 = p1 < 32 ? g0[32 + p1] : 0xFFFFFFFFu; }
                else         { p0++; h0 = p0 < 32 ? g0[p0]      : 0xFFFFFFFFu; }
            } else {
                if (h3 < h2) { p3++; h3 = p3 < 32 ? g0[96 + p3] : 0xFFFFFFFFu; }
                else         { p2++; h2 = p2 < 32 ? g0[64 + p2] : 0xFFFFFFFFu; }
            }
        }
    }
}

// ---------------------------------------------------------------------------
// K2: fused edge MLP — now 4 POINTS PER WAVE (16/block, grid 4096).
// Same transposed-layer-2 / fp8-layer-3 structure; per chunk the shared w3
// B-frag feeds 4 edge M-tiles (8 MFMA), halving w3 L2 traffic + prefetch
// VALU per point.  Epilogue slimmed: 4 max3-shaped fmax chains over all 64
// values, no shfl_xor (both half-wave lanes atomicMax the same LDS slot),
// 1/4096 un-scaling folded into the FC head.
// ---------------------------------------------------------------------------
__global__ __launch_bounds__(256, 3) void mlp_kernel(
    const float* __restrict__ x, const unsigned short* __restrict__ idxb,
    const float* __restrict__ w1, const float* __restrict__ b1,
    const float* __restrict__ b2,
    const bf16_t* __restrict__ w2sw, const unsigned char* __restrict__ w3f8,
    unsigned* __restrict__ g_enc)
{
    __shared__ unsigned gl[1024];                 // 4096 B
    __shared__ __align__(16) float4 w1l[64];      // 1024 B
    __shared__ __align__(16) float b2s[128];      // 512 B  (= 256*b2)

    const int tid = threadIdx.x;
    const int b   = blockIdx.x >> 8;          // 256 blocks per batch
    const int p0  = (blockIdx.x & 255) * 16;  // first point
    const float* xb = x + b * 3 * N_;

    const int wv = tid >> 6;
    const int l  = tid & 63;
    const int lm = l & 31;
    const int hi = l >> 5;

    for (int i = tid; i < 1024; i += 256) gl[i] = 0u;
    if (tid < 64)
        w1l[tid] = make_float4(w1[tid * 3], w1[tid * 3 + 1], w1[tid * 3 + 2], b1[tid]);
    else if (tid < 192)
        b2s[tid - 64] = 256.0f * b2[tid - 64];
    __syncthreads();

    // ---- prefetch layer-3 B chunk 0 (in flight during gathers + layers 1+2)
    const uint4* w3v = (const uint4*)w3f8;
    intx8 bwA[2], bwB[2];
    #pragma unroll
    for (int mt2 = 0; mt2 < 4; mt2++) {
        const uint4 v = w3v[mt2 * 64 + l];
        bwA[mt2 >> 1][(mt2 & 1) * 4 + 0] = (int)v.x;
        bwA[mt2 >> 1][(mt2 & 1) * 4 + 1] = (int)v.y;
        bwA[mt2 >> 1][(mt2 & 1) * 4 + 2] = (int)v.z;
        bwA[mt2 >> 1][(mt2 & 1) * 4 + 3] = (int)v.w;
    }

    // ---- gather edge features for all 4 points up front (latency overlap)
    float d0[4], d1[4], d2[4];
    #pragma unroll
    for (int nt = 0; nt < 4; nt++) {
        const int pp = p0 + wv * 4 + nt;                 // wave-uniform point
        const int j  = idxb[((size_t)(b * N_ + pp)) * K_ + lm];
        d0[nt] = xb[j]          - xb[pp];
        d1[nt] = xb[N_ + j]     - xb[N_ + pp];
        d2[nt] = xb[2 * N_ + j] - xb[2 * N_ + pp];
    }

    // ---- layers 1+2 per point-pair -> a3v (fp8 A-frags for layer 3) ----
    intx8 a3v[4][2];   // [nt][kq]; byte map matches w3f8
    #pragma unroll
    for (int pr = 0; pr < 2; pr++) {
        // layer 1 (VALU) -> h1 B-frags (edges as N)
        bf16x8 b1h[2][4];   // [nt2][ks]
        #pragma unroll
        for (int ks = 0; ks < 4; ks++)
            #pragma unroll
            for (int jj = 0; jj < 8; jj++) {
                const float4 w = w1l[ks * 16 + hi * 8 + jj];
                #pragma unroll
                for (int nt2 = 0; nt2 < 2; nt2++)
                    b1h[nt2][ks][jj] = (bf16_t)fmaxf(
                        fmaf(w.z, d2[pr * 2 + nt2],
                        fmaf(w.y, d1[pr * 2 + nt2],
                        fmaf(w.x, d0[pr * 2 + nt2], w.w))), 0.f);
            }

        // layer 2 (MFMA 32x32x16 bf16, transposed) + fused fp8 pack
        #pragma unroll
        for (int mt2 = 0; mt2 < 4; mt2++) {          // channel tile (M side)
            floatx16 acc0 = (floatx16)0.f, acc1 = (floatx16)0.f;
            #pragma unroll
            for (int ks = 0; ks < 4; ks++) {
                const bf16x8 aw = *(const bf16x8*)&w2sw[((mt2 * 4 + ks) * 64 + l) * 8];
                acc0 = __builtin_amdgcn_mfma_f32_32x32x16_bf16(aw, b1h[0][ks], acc0, 0, 0, 0);
                acc1 = __builtin_amdgcn_mfma_f32_32x32x16_bf16(aw, b1h[1][ks], acc1, 0, 0, 0);
            }
            const int kq = mt2 >> 1, c0i = (mt2 & 1) * 4;
            #pragma unroll
            for (int i2 = 0; i2 < 4; i2++) {
                const float4 bb = *(const float4*)&b2s[mt2 * 32 + i2 * 8 + hi * 4];
                {
                    const float v0 = fmaxf(fmaf(acc0[4 * i2 + 0], 256.f, bb.x), 0.f);
                    const float v1 = fmaxf(fmaf(acc0[4 * i2 + 1], 256.f, bb.y), 0.f);
                    const float v2 = fmaxf(fmaf(acc0[4 * i2 + 2], 256.f, bb.z), 0.f);
                    const float v3 = fmaxf(fmaf(acc0[4 * i2 + 3], 256.f, bb.w), 0.f);
                    int w = __builtin_amdgcn_cvt_pk_fp8_f32(v0, v1, 0, false);
                    w = __builtin_amdgcn_cvt_pk_fp8_f32(v2, v3, w, true);
                    a3v[pr * 2 + 0][kq][c0i + i2] = w;
                }
                {
                    const float v0 = fmaxf(fmaf(acc1[4 * i2 + 0], 256.f, bb.x), 0.f);
                    const float v1 = fmaxf(fmaf(acc1[4 * i2 + 1], 256.f, bb.y), 0.f);
                    const float v2 = fmaxf(fmaf(acc1[4 * i2 + 2], 256.f, bb.z), 0.f);
                    const float v3 = fmaxf(fmaf(acc1[4 * i2 + 3], 256.f, bb.w), 0.f);
                    int w = __builtin_amdgcn_cvt_pk_fp8_f32(v0, v1, 0, false);
                    w = __builtin_amdgcn_cvt_pk_fp8_f32(v2, v3, w, true);
                    a3v[pr * 2 + 1][kq][c0i + i2] = w;
                }
            }
        }
    }

    // ---- layer 3: 32 chunks of 32 out-channels; scaled fp8 MFMA (K=64),
    //      shared B across 4 edge M-tiles, uint4 B prefetch double-buffered
    #pragma unroll 1
    for (int cc = 0; cc < 16; cc++) {
        #pragma unroll
        for (int half = 0; half < 2; half++) {
            const int cb = cc * 2 + half;       // 0..31
            intx8* cur = half ? bwB : bwA;
            intx8* nxt = half ? bwA : bwB;
            if (cb < 31) {
                #pragma unroll
                for (int mt2 = 0; mt2 < 4; mt2++) {
                    const uint4 v = w3v[((cb + 1) * 4 + mt2) * 64 + l];
                    nxt[mt2 >> 1][(mt2 & 1) * 4 + 0] = (int)v.x;
                    nxt[mt2 >> 1][(mt2 & 1) * 4 + 1] = (int)v.y;
                    nxt[mt2 >> 1][(mt2 & 1) * 4 + 2] = (int)v.z;
                    nxt[mt2 >> 1][(mt2 & 1) * 4 + 3] = (int)v.w;
                }
            }
            float c0, c1, c2, c3;
            #pragma unroll
            for (int mtp = 0; mtp < 2; mtp++) {
                floatx16 aA = (floatx16)0.f, aB = (floatx16)0.f;
                #pragma unroll
                for (int kq = 0; kq < 2; kq++) {
                    aA = __builtin_amdgcn_mfma_scale_f32_32x32x64_f8f6f4(
                        a3v[2 * mtp + 0][kq], cur[kq], aA,
                        0, 0, 0, 0x7F7F7F7F, 0, 0x7F7F7F7F);
                    aB = __builtin_amdgcn_mfma_scale_f32_32x32x64_f8f6f4(
                        a3v[2 * mtp + 1][kq], cur[kq], aB,
                        0, 0, 0, 0x7F7F7F7F, 0, 0x7F7F7F7F);
                }
                // 4 independent chains, shaped as fmax(fmax(a,b),c) -> v_max3
                if (mtp == 0) {
                    c0 = fmaxf(aA[0], aB[0]);
                    c1 = fmaxf(aA[1], aB[1]);
                    c2 = fmaxf(aA[2], aB[2]);
                    c3 = fmaxf(aA[3], aB[3]);
                    #pragma unroll
                    for (int o = 4; o < 16; o += 4) {
                        c0 = fmaxf(fmaxf(aA[o + 0], aB[o + 0]), c0);
                        c1 = fmaxf(fmaxf(aA[o + 1], aB[o + 1]), c1);
                        c2 = fmaxf(fmaxf(aA[o + 2], aB[o + 2]), c2);
                        c3 = fmaxf(fmaxf(aA[o + 3], aB[o + 3]), c3);
                    }
                } else {
                    #pragma unroll
                    for (int o = 0; o < 16; o += 4) {
                        c0 = fmaxf(fmaxf(aA[o + 0], aB[o + 0]), c0);
                        c1 = fmaxf(fmaxf(aA[o + 1], aB[o + 1]), c1);
                        c2 = fmaxf(fmaxf(aA[o + 2], aB[o + 2]), c2);
                        c3 = fmaxf(fmaxf(aA[o + 3], aB[o + 3]), c3);
                    }
                }
            }
            const float m = fmaxf(fmaxf(c0, c1), fmaxf(c2, c3));
            // both half-wave lanes hit the same slot: cross-half merge via DS
            atomicMax(&gl[cb * 32 + lm], enc_f(m));
        }
    }

    __syncthreads();
    for (int i = tid; i < 1024; i += 256)
        atomicMax(&g_enc[b * 1024 + i], gl[i]);
}

// ---------------------------------------------------------------------------
// K3: FC head per batch. grid 16 x 256.  (now also undoes the 4096x scale)
// ---------------------------------------------------------------------------
__global__ __launch_bounds__(256) void head_kernel(
    const unsigned* __restrict__ g_enc, const float* __restrict__ b3,
    const float* __restrict__ fw1, const float* __restrict__ fb1,
    const float* __restrict__ fw2, const float* __restrict__ fb2,
    const float* __restrict__ fw3, const float* __restrict__ fb3,
    float* __restrict__ tmat)
{
    __shared__ __align__(16) float g[1024];
    __shared__ __align__(16) float f1[512];
    __shared__ __align__(16) float f2[256];
    const int t = threadIdx.x, b = blockIdx.x;

    for (int i = t; i < 1024; i += 256)
        g[i] = fmaxf(fmaf(dec_f(g_enc[b * 1024 + i]), 2.44140625e-4f, b3[i]), 0.f);
    __syncthreads();

    for (int o = t; o < 512; o += 256) {
        const float4* wr = (const float4*)(fw1 + (size_t)o * 1024);
        const float4* gv = (const float4*)g;
        float acc = fb1[o];
        for (int i = 0; i < 256; i++) {
            float4 a = wr[i], c = gv[i];
            acc = fmaf(a.x, c.x, acc); acc = fmaf(a.y, c.y, acc);
            acc = fmaf(a.z, c.z, acc); acc = fmaf(a.w, c.w, acc);
        }
        f1[o] = fmaxf(acc, 0.f);
    }
    __syncthreads();
    {
        const int o = t;
        const float4* wr = (const float4*)(fw2 + (size_t)o * 512);
        const float4* fv = (const float4*)f1;
        float acc = fb2[o];
        for (int i = 0; i < 128; i++) {
            float4 a = wr[i], c = fv[i];
            acc = fmaf(a.x, c.x, acc); acc = fmaf(a.y, c.y, acc);
            acc = fmaf(a.z, c.z, acc); acc = fmaf(a.w, c.w, acc);
        }
        f2[o] = fmaxf(acc, 0.f);
    }
    __syncthreads();
    if (t < 9) {
        const float4* wr = (const float4*)(fw3 + (size_t)t * 256);
        const float4* fv = (const float4*)f2;
        float acc = fb3[t];
        for (int i = 0; i < 64; i++) {
            float4 a = wr[i], c = fv[i];
            acc = fmaf(a.x, c.x, acc); acc = fmaf(a.y, c.y, acc);
            acc = fmaf(a.z, c.z, acc); acc = fmaf(a.w, c.w, acc);
        }
        if (t == 0 || t == 4 || t == 8) acc += 1.f;
        tmat[b * 9 + t] = acc;
    }
}

// ---------------------------------------------------------------------------
// K4: out[b][d][n] = sum_c x[b][c][n] * t[b][c][d].  grid 256 x 256.
// ---------------------------------------------------------------------------
__global__ __launch_bounds__(256) void out_kernel(
    const float* __restrict__ x, const float* __restrict__ tmat,
    float* __restrict__ out)
{
    const int gid = blockIdx.x * 256 + threadIdx.x;
    const int b = gid >> 12, n = gid & 4095;
    const float* T = tmat + b * 9;
    const float x0 = x[b * 12288 + n];
    const float x1 = x[b * 12288 + 4096 + n];
    const float x2 = x[b * 12288 + 8192 + n];
    #pragma unroll
    for (int d = 0; d < 3; d++)
        out[b * 12288 + d * 4096 + n] =
            fmaf(x2, T[6 + d], fmaf(x1, T[3 + d], x0 * T[d]));
}

extern "C" void kernel_launch(void* const* d_in, const int* in_sizes, int n_in,
                              void* d_out, int out_size, void* d_ws, size_t ws_size,
                              hipStream_t stream) {
    const float* x   = (const float*)d_in[0];
    const float* w1  = (const float*)d_in[1];
    const float* b1  = (const float*)d_in[2];
    const float* w2  = (const float*)d_in[3];
    const float* b2  = (const float*)d_in[4];
    const float* w3  = (const float*)d_in[5];
    const float* b3  = (const float*)d_in[6];
    const float* fw1 = (const float*)d_in[7];
    const float* fb1 = (const float*)d_in[8];
    const float* fw2 = (const float*)d_in[9];
    const float* fb2 = (const float*)d_in[10];
    const float* fw3 = (const float*)d_in[11];
    const float* fb3 = (const float*)d_in[12];
    float* out = (float*)d_out;

    char* ws = (char*)d_ws;
    unsigned short* idxb = (unsigned short*)ws;
    unsigned* g_enc = (unsigned*)(ws + 4194304);
    unsigned char* w3f8 = (unsigned char*)(ws + 4259840);
    bf16_t* w2sw = (bf16_t*)(ws + 4390912);
    float* tmat  = (float*)(ws + 4407296);

    knn_kernel<<<2048, 512, 0, stream>>>(x, w3, w2, idxb, g_enc, w3f8, w2sw);
    mlp_kernel<<<4096, 256, 0, stream>>>(x, idxb, w1, b1, b2, w2sw, w3f8, g_enc);
    head_kernel<<<16, 256, 0, stream>>>(g_enc, b3, fw1, fb1, fw2, fb2, fw3, fb3, tmat);
    out_kernel<<<256, 256, 0, stream>>>(x, tmat, out);
}

// Round 2
// 558.840 us; speedup vs baseline: 1.2421x; 1.2421x over previous
//
#include <hip/hip_runtime.h>
#include <hip/hip_fp8.h>

typedef __bf16 bf16_t;
typedef __bf16 bf16x8 __attribute__((ext_vector_type(8)));
typedef float floatx16 __attribute__((ext_vector_type(16)));
typedef int intx8 __attribute__((ext_vector_type(8)));
typedef unsigned long long u64;

#define B_ 16
#define N_ 4096
#define K_ 32

// ws layout (bytes):
//   idx   u16 [16][4096][32]         @ 0        (4194304)
//   g_enc u32 [16][1024]             @ 4194304  (65536)
//   w3f8  fp8 frag-major [131072]    @ 4259840  (131072)   (= w3 * 16)
//   w2sw  bf16 frag-major [8192]     @ 4390912  (16384)
//   tmat  f32 [16][9]                @ 4407296  (576)

__device__ __forceinline__ unsigned enc_f(float f) {
    unsigned u = __float_as_uint(f);
    return (u & 0x80000000u) ? ~u : (u | 0x80000000u);
}
__device__ __forceinline__ float dec_f(unsigned e) {
    return __uint_as_float((e & 0x80000000u) ? (e & 0x7fffffffu) : ~e);
}

// ---------------------------------------------------------------------------
// K1: kNN top-32 (r13 core, unchanged).  16 threads/query x 256 candidates,
// register top-8, unconditional med3-chain insert, two-level 4-way merges.
// grid 2048 x 512.  Side jobs: zero g_enc, build w3f8 + w2sw.
// ---------------------------------------------------------------------------
__global__ __launch_bounds__(512, 4) void knn_kernel(
    const float* __restrict__ x, const float* __restrict__ w3,
    const float* __restrict__ w2, unsigned short* __restrict__ idxb,
    unsigned* __restrict__ g_enc, unsigned char* __restrict__ w3f8,
    bf16_t* __restrict__ w2sw)
{
    __shared__ __align__(16) float4 cand[16 * 257];   // 65792 B
    unsigned* lists = (unsigned*)cand;                // reused after scan
    unsigned* m1 = ((unsigned*)cand) + 8192;          // merge scratch @ 32 KB
    const int tid = threadIdx.x;
    const int bid = blockIdx.x;  // 2048 blocks

    {
        const int g = bid * 512 + tid;
        if (g < 131072) {
            const int q = g & 15, lI = (g >> 4) & 63, mt2 = (g >> 10) & 3, cb = g >> 12;
            const int lmI = lI & 31, hiI = lI >> 5;
            const int ch = mt2 * 32 + (q & 3) + 8 * (q >> 2) + 4 * hiI;
            __hip_fp8_e4m3 t(16.0f * w3[(cb * 32 + lmI) * 128 + ch]);
            w3f8[g] = t.__x;
        } else if (g < 139264) {
            const int o = g - 131072;
            const int f = o >> 9, r = o & 511, lI = r >> 3, jj = r & 7;
            const int ks = f & 3, nb = f >> 2, lmI = lI & 31, hiI = lI >> 5;
            w2sw[o] = (bf16_t)w2[(nb * 32 + lmI) * 64 + ks * 16 + hiI * 8 + jj];
        } else if (g < 155648) {
            g_enc[g - 139264] = 0u;
        }
    }

    const int b  = bid >> 7;                    // 128 blocks per batch
    const int q  = tid >> 4;                    // local query 0..31
    const int n  = (bid & 127) * 32 + q;        // global query index
    const int t  = tid & 15;                    // candidate chunk
    const float* xb = x + b * 3 * N_;

    for (int j = tid; j < N_; j += 512) {
        float cx = xb[j], cy = xb[N_ + j], cz = xb[2 * N_ + j];
        cand[j + (j >> 8)] = make_float4(-2.f * cx, -2.f * cy, -2.f * cz,
                                         fmaf(cx, cx, fmaf(cy, cy, cz * cz)));
    }
    __syncthreads();

    const float xi0 = xb[n], xi1 = xb[N_ + n], xi2 = xb[2 * N_ + n];
    const float xisq1 = fmaf(xi0, xi0, fmaf(xi1, xi1, xi2 * xi2)) + 1.0f;

    unsigned r[8];
    #pragma unroll
    for (int s = 0; s < 8; s++) r[s] = 0x7F7FFFFFu;   // FLT_MAX sentinel

    const int j0 = t * 256;
    const int pb = t * 257;
    #pragma unroll 8
    for (int jj = 0; jj < 256; jj++) {
        const float4 c = cand[pb + jj];
        const float d = fmaf(c.z, xi2, fmaf(c.y, xi1, fmaf(c.x, xi0, c.w)));
        const unsigned key =
            (__float_as_uint(d + xisq1) & 0xFFFFF000u) | (unsigned)(j0 + jj);
        #pragma unroll
        for (int s = 7; s >= 1; s--) {
            const unsigned hv = r[s - 1] > key ? r[s - 1] : key;
            r[s] = r[s] < hv ? r[s] : hv;           // med3
        }
        r[0] = r[0] < key ? r[0] : key;
    }
    __syncthreads();

    #pragma unroll
    for (int k = 0; k < 8; k++) lists[tid * 9 + k] = r[k];
    __syncthreads();

    if (tid < 128) {
        const int q1 = tid >> 2, gi = tid & 3;
        const int base = (q1 * 16 + gi * 4) * 9;
        unsigned h0 = lists[base], h1 = lists[base + 9];
        unsigned h2 = lists[base + 18], h3 = lists[base + 27];
        int p0 = 0, p1 = 0, p2 = 0, p3 = 0;
        unsigned* outp = m1 + (q1 * 4 + gi) * 32;
        #pragma unroll 1
        for (int k = 0; k < 32; k++) {
            const unsigned m01 = h0 < h1 ? h0 : h1;
            const unsigned m23 = h2 < h3 ? h2 : h3;
            const unsigned v = m01 < m23 ? m01 : m23;
            outp[k] = v;
            if (m01 < m23) {
                if (h1 < h0) { p1++; h1 = p1 < 8 ? lists[base + 9 + p1] : 0xFFFFFFFFu; }
                else         { p0++; h0 = p0 < 8 ? lists[base + p0]     : 0xFFFFFFFFu; }
            } else {
                if (h3 < h2) { p3++; h3 = p3 < 8 ? lists[base + 27 + p3] : 0xFFFFFFFFu; }
                else         { p2++; h2 = p2 < 8 ? lists[base + 18 + p2] : 0xFFFFFFFFu; }
            }
        }
    }
    __syncthreads();

    if (tid < 32) {
        const unsigned* g0 = m1 + tid * 128;
        unsigned h0 = g0[0], h1 = g0[32], h2 = g0[64], h3 = g0[96];
        int p0 = 0, p1 = 0, p2 = 0, p3 = 0;
        const int nq = (bid & 127) * 32 + tid;
        unsigned short* op = idxb + ((size_t)(b * N_ + nq)) * K_;
        #pragma unroll 1
        for (int k = 0; k < K_; k++) {
            const unsigned m01 = h0 < h1 ? h0 : h1;
            const unsigned m23 = h2 < h3 ? h2 : h3;
            const unsigned v = m01 < m23 ? m01 : m23;
            op[k] = (unsigned short)(v & 0xFFFu);
            if (m01 < m23) {
                if (h1 < h0) { p1++; h1 = p1 < 32 ? g0[32 + p1] : 0xFFFFFFFFu; }
                else         { p0++; h0 = p0 < 32 ? g0[p0]      : 0xFFFFFFFFu; }
            } else {
                if (h3 < h2) { p3++; h3 = p3 < 32 ? g0[96 + p3] : 0xFFFFFFFFu; }
                else         { p2++; h2 = p2 < 32 ? g0[64 + p2] : 0xFFFFFFFFu; }
            }
        }
    }
}

// ---------------------------------------------------------------------------
// K2: fused edge MLP (round-0 verified structure: 2 points/wave, grid 8192,
// VGPR=60, no spill).  Changes vs round-0, all VALU-side only:
//   - epilogue: 4 max3-shaped fmax chains (no t16/t8/t4 tree), no shfl_xor,
//     no hi==0 branch (both half-wave lanes atomicMax the same LDS slot),
//     no 1/4096 mul (folded into head_kernel).
//   - s_setprio(1) around the layer-3 MFMA cluster (independent waves,
//     attn-like regime where setprio measured +4-7%).
// ---------------------------------------------------------------------------
__global__ __launch_bounds__(256, 3) void mlp_kernel(
    const float* __restrict__ x, const unsigned short* __restrict__ idxb,
    const float* __restrict__ w1, const float* __restrict__ b1,
    const float* __restrict__ b2,
    const bf16_t* __restrict__ w2sw, const unsigned char* __restrict__ w3f8,
    unsigned* __restrict__ g_enc)
{
    __shared__ unsigned gl[1024];                 // 4096 B
    __shared__ __align__(16) float4 w1l[64];      // 1024 B
    __shared__ __align__(16) float b2s[128];      // 512 B  (= 256*b2)

    const int tid = threadIdx.x;
    const int b   = blockIdx.x >> 9;          // 512 blocks per batch
    const int p0  = (blockIdx.x & 511) * 8;   // first point
    const float* xb = x + b * 3 * N_;

    const int wv = tid >> 6;
    const int l  = tid & 63;
    const int lm = l & 31;
    const int hi = l >> 5;

    for (int i = tid; i < 1024; i += 256) gl[i] = 0u;
    if (tid < 64)
        w1l[tid] = make_float4(w1[tid * 3], w1[tid * 3 + 1], w1[tid * 3 + 2], b1[tid]);
    else if (tid < 192)
        b2s[tid - 64] = 256.0f * b2[tid - 64];
    __syncthreads();

    // ---- prefetch layer-3 B chunk 0 (in flight during layers 1+2) ----
    const uint4* w3v = (const uint4*)w3f8;
    intx8 bwA[2], bwB[2];
    #pragma unroll
    for (int mt2 = 0; mt2 < 4; mt2++) {
        const uint4 v = w3v[mt2 * 64 + l];
        bwA[mt2 >> 1][(mt2 & 1) * 4 + 0] = (int)v.x;
        bwA[mt2 >> 1][(mt2 & 1) * 4 + 1] = (int)v.y;
        bwA[mt2 >> 1][(mt2 & 1) * 4 + 2] = (int)v.z;
        bwA[mt2 >> 1][(mt2 & 1) * 4 + 3] = (int)v.w;
    }

    // ---- layer 1 (VALU) -> h1 B-frags (edges as N) ----
    bf16x8 b1h[2][4];   // [nt2][ks]; B[n=lm (edge of point nt2)][k=ks*16+hi*8+jj]
    float d0[2], d1[2], d2[2];
    #pragma unroll
    for (int nt2 = 0; nt2 < 2; nt2++) {
        const int pp = p0 + wv * 2 + nt2;                // wave-uniform point
        const int j  = idxb[((size_t)(b * N_ + pp)) * K_ + lm];
        d0[nt2] = xb[j]          - xb[pp];
        d1[nt2] = xb[N_ + j]     - xb[N_ + pp];
        d2[nt2] = xb[2 * N_ + j] - xb[2 * N_ + pp];
    }
    #pragma unroll
    for (int ks = 0; ks < 4; ks++)
        #pragma unroll
        for (int jj = 0; jj < 8; jj++) {
            const float4 w = w1l[ks * 16 + hi * 8 + jj];
            #pragma unroll
            for (int nt2 = 0; nt2 < 2; nt2++)
                b1h[nt2][ks][jj] = (bf16_t)fmaxf(
                    fmaf(w.z, d2[nt2], fmaf(w.y, d1[nt2], fmaf(w.x, d0[nt2], w.w))), 0.f);
        }

    // ---- layer 2 (MFMA 32x32x16 bf16, transposed) + fused fp8 pack -> a3v ----
    intx8 a3v[2][2];   // [nt2 = edge m-tile][kq]; byte map matches w3f8
    #pragma unroll
    for (int mt2 = 0; mt2 < 4; mt2++) {          // channel tile (M side)
        floatx16 acc0 = (floatx16)0.f, acc1 = (floatx16)0.f;
        #pragma unroll
        for (int ks = 0; ks < 4; ks++) {
            const bf16x8 aw = *(const bf16x8*)&w2sw[((mt2 * 4 + ks) * 64 + l) * 8];
            acc0 = __builtin_amdgcn_mfma_f32_32x32x16_bf16(aw, b1h[0][ks], acc0, 0, 0, 0);
            acc1 = __builtin_amdgcn_mfma_f32_32x32x16_bf16(aw, b1h[1][ks], acc1, 0, 0, 0);
        }
        const int kq = mt2 >> 1, c0 = (mt2 & 1) * 4;
        #pragma unroll
        for (int i2 = 0; i2 < 4; i2++) {
            // channels mt2*32 + 8*i2 + 4*hi + {0..3}  (lane-uniform per hi)
            const float4 bb = *(const float4*)&b2s[mt2 * 32 + i2 * 8 + hi * 4];
            {
                const float v0 = fmaxf(fmaf(acc0[4 * i2 + 0], 256.f, bb.x), 0.f);
                const float v1 = fmaxf(fmaf(acc0[4 * i2 + 1], 256.f, bb.y), 0.f);
                const float v2 = fmaxf(fmaf(acc0[4 * i2 + 2], 256.f, bb.z), 0.f);
                const float v3 = fmaxf(fmaf(acc0[4 * i2 + 3], 256.f, bb.w), 0.f);
                int w = __builtin_amdgcn_cvt_pk_fp8_f32(v0, v1, 0, false);
                w = __builtin_amdgcn_cvt_pk_fp8_f32(v2, v3, w, true);
                a3v[0][kq][c0 + i2] = w;
            }
            {
                const float v0 = fmaxf(fmaf(acc1[4 * i2 + 0], 256.f, bb.x), 0.f);
                const float v1 = fmaxf(fmaf(acc1[4 * i2 + 1], 256.f, bb.y), 0.f);
                const float v2 = fmaxf(fmaf(acc1[4 * i2 + 2], 256.f, bb.z), 0.f);
                const float v3 = fmaxf(fmaf(acc1[4 * i2 + 3], 256.f, bb.w), 0.f);
                int w = __builtin_amdgcn_cvt_pk_fp8_f32(v0, v1, 0, false);
                w = __builtin_amdgcn_cvt_pk_fp8_f32(v2, v3, w, true);
                a3v[1][kq][c0 + i2] = w;
            }
        }
    }

    // ---- layer 3: 32 chunks of 32 out-channels; scaled fp8 MFMA (K=64),
    //      uint4 B prefetch double-buffered, NO barriers ----
    #pragma unroll 1
    for (int cc = 0; cc < 16; cc++) {
        #pragma unroll
        for (int half = 0; half < 2; half++) {
            const int cb = cc * 2 + half;       // 0..31
            intx8* cur = half ? bwB : bwA;
            intx8* nxt = half ? bwA : bwB;
            if (cb < 31) {
                #pragma unroll
                for (int mt2 = 0; mt2 < 4; mt2++) {
                    const uint4 v = w3v[((cb + 1) * 4 + mt2) * 64 + l];
                    nxt[mt2 >> 1][(mt2 & 1) * 4 + 0] = (int)v.x;
                    nxt[mt2 >> 1][(mt2 & 1) * 4 + 1] = (int)v.y;
                    nxt[mt2 >> 1][(mt2 & 1) * 4 + 2] = (int)v.z;
                    nxt[mt2 >> 1][(mt2 & 1) * 4 + 3] = (int)v.w;
                }
            }
            floatx16 acc3[2];
            acc3[0] = (floatx16)0.f; acc3[1] = (floatx16)0.f;
            __builtin_amdgcn_s_setprio(1);
            #pragma unroll
            for (int kq = 0; kq < 2; kq++)
                #pragma unroll
                for (int mt3 = 0; mt3 < 2; mt3++)
                    acc3[mt3] = __builtin_amdgcn_mfma_scale_f32_32x32x64_f8f6f4(
                        a3v[mt3][kq], cur[kq], acc3[mt3],
                        0, 0,                      // cbsz=fp8, blgp=fp8
                        0, 0x7F7F7F7F,             // scale A = 1.0 (E8M0 127)
                        0, 0x7F7F7F7F);            // scale B = 1.0
            __builtin_amdgcn_s_setprio(0);
            // 4 independent max3-shaped chains over the 32 values.
            // Scaling (1/(256*16)) folded into head_kernel.
            float c0 = fmaxf(acc3[0][0], acc3[1][0]);
            float c1 = fmaxf(acc3[0][1], acc3[1][1]);
            float c2 = fmaxf(acc3[0][2], acc3[1][2]);
            float c3 = fmaxf(acc3[0][3], acc3[1][3]);
            #pragma unroll
            for (int o = 4; o < 16; o += 4) {
                c0 = fmaxf(fmaxf(acc3[0][o + 0], acc3[1][o + 0]), c0);
                c1 = fmaxf(fmaxf(acc3[0][o + 1], acc3[1][o + 1]), c1);
                c2 = fmaxf(fmaxf(acc3[0][o + 2], acc3[1][o + 2]), c2);
                c3 = fmaxf(fmaxf(acc3[0][o + 3], acc3[1][o + 3]), c3);
            }
            const float m = fmaxf(fmaxf(c0, c1), fmaxf(c2, c3));
            // both half-wave lanes hit the same slot: cross-half merge in DS
            atomicMax(&gl[cb * 32 + lm], enc_f(m));
        }
    }

    __syncthreads();
    for (int i = tid; i < 1024; i += 256)
        atomicMax(&g_enc[b * 1024 + i], gl[i]);
}

// ---------------------------------------------------------------------------
// K3: FC head per batch. grid 16 x 256.  (undoes the 4096x edge-MLP scale)
// ---------------------------------------------------------------------------
__global__ __launch_bounds__(256) void head_kernel(
    const unsigned* __restrict__ g_enc, const float* __restrict__ b3,
    const float* __restrict__ fw1, const float* __restrict__ fb1,
    const float* __restrict__ fw2, const float* __restrict__ fb2,
    const float* __restrict__ fw3, const float* __restrict__ fb3,
    float* __restrict__ tmat)
{
    __shared__ __align__(16) float g[1024];
    __shared__ __align__(16) float f1[512];
    __shared__ __align__(16) float f2[256];
    const int t = threadIdx.x, b = blockIdx.x;

    for (int i = t; i < 1024; i += 256)
        g[i] = fmaxf(fmaf(dec_f(g_enc[b * 1024 + i]), 2.44140625e-4f, b3[i]), 0.f);
    __syncthreads();

    for (int o = t; o < 512; o += 256) {
        const float4* wr = (const float4*)(fw1 + (size_t)o * 1024);
        const float4* gv = (const float4*)g;
        float acc = fb1[o];
        for (int i = 0; i < 256; i++) {
            float4 a = wr[i], c = gv[i];
            acc = fmaf(a.x, c.x, acc); acc = fmaf(a.y, c.y, acc);
            acc = fmaf(a.z, c.z, acc); acc = fmaf(a.w, c.w, acc);
        }
        f1[o] = fmaxf(acc, 0.f);
    }
    __syncthreads();
    {
        const int o = t;
        const float4* wr = (const float4*)(fw2 + (size_t)o * 512);
        const float4* fv = (const float4*)f1;
        float acc = fb2[o];
        for (int i = 0; i < 128; i++) {
            float4 a = wr[i], c = fv[i];
            acc = fmaf(a.x, c.x, acc); acc = fmaf(a.y, c.y, acc);
            acc = fmaf(a.z, c.z, acc); acc = fmaf(a.w, c.w, acc);
        }
        f2[o] = fmaxf(acc, 0.f);
    }
    __syncthreads();
    if (t < 9) {
        const float4* wr = (const float4*)(fw3 + (size_t)t * 256);
        const float4* fv = (const float4*)f2;
        float acc = fb3[t];
        for (int i = 0; i < 64; i++) {
            float4 a = wr[i], c = fv[i];
            acc = fmaf(a.x, c.x, acc); acc = fmaf(a.y, c.y, acc);
            acc = fmaf(a.z, c.z, acc); acc = fmaf(a.w, c.w, acc);
        }
        if (t == 0 || t == 4 || t == 8) acc += 1.f;
        tmat[b * 9 + t] = acc;
    }
}

// ---------------------------------------------------------------------------
// K4: out[b][d][n] = sum_c x[b][c][n] * t[b][c][d].  grid 256 x 256.
// ---------------------------------------------------------------------------
__global__ __launch_bounds__(256) void out_kernel(
    const float* __restrict__ x, const float* __restrict__ tmat,
    float* __restrict__ out)
{
    const int gid = blockIdx.x * 256 + threadIdx.x;
    const int b = gid >> 12, n = gid & 4095;
    const float* T = tmat + b * 9;
    const float x0 = x[b * 12288 + n];
    const float x1 = x[b * 12288 + 4096 + n];
    const float x2 = x[b * 12288 + 8192 + n];
    #pragma unroll
    for (int d = 0; d < 3; d++)
        out[b * 12288 + d * 4096 + n] =
            fmaf(x2, T[6 + d], fmaf(x1, T[3 + d], x0 * T[d]));
}

extern "C" void kernel_launch(void* const* d_in, const int* in_sizes, int n_in,
                              void* d_out, int out_size, void* d_ws, size_t ws_size,
                              hipStream_t stream) {
    const float* x   = (const float*)d_in[0];
    const float* w1  = (const float*)d_in[1];
    const float* b1  = (const float*)d_in[2];
    const float* w2  = (const float*)d_in[3];
    const float* b2  = (const float*)d_in[4];
    const float* w3  = (const float*)d_in[5];
    const float* b3  = (const float*)d_in[6];
    const float* fw1 = (const float*)d_in[7];
    const float* fb1 = (const float*)d_in[8];
    const float* fw2 = (const float*)d_in[9];
    const float* fb2 = (const float*)d_in[10];
    const float* fw3 = (const float*)d_in[11];
    const float* fb3 = (const float*)d_in[12];
    float* out = (float*)d_out;

    char* ws = (char*)d_ws;
    unsigned short* idxb = (unsigned short*)ws;
    unsigned* g_enc = (unsigned*)(ws + 4194304);
    unsigned char* w3f8 = (unsigned char*)(ws + 4259840);
    bf16_t* w2sw = (bf16_t*)(ws + 4390912);
    float* tmat  = (float*)(ws + 4407296);

    knn_kernel<<<2048, 512, 0, stream>>>(x, w3, w2, idxb, g_enc, w3f8, w2sw);
    mlp_kernel<<<8192, 256, 0, stream>>>(x, idxb, w1, b1, b2, w2sw, w3f8, g_enc);
    head_kernel<<<16, 256, 0, stream>>>(g_enc, b3, fw1, fb1, fw2, fb2, fw3, fb3, tmat);
    out_kernel<<<256, 256, 0, stream>>>(x, tmat, out);
}